// Round 6
// baseline (66.644 us; speedup 1.0000x reference)
//
#include <hip/hip_runtime.h>

// ---------- types ----------
using f32x4  = __attribute__((ext_vector_type(4))) float;
using bf16x8 = __attribute__((ext_vector_type(8))) short;   // 8 bf16 in 4 VGPRs

__device__ __forceinline__ unsigned short f2bf(float f) {
    union { float f; unsigned int u; } v; v.f = f;
    unsigned int r = v.u + 0x7fffu + ((v.u >> 16) & 1u);  // RNE
    return (unsigned short)(r >> 16);
}

__device__ __forceinline__ float bf2f(unsigned short u) {
    union { unsigned int u; float f; } v; v.u = ((unsigned int)u) << 16;
    return v.f;
}

// ---------- transpose D [16][256c][256q] f32 -> Dt [16][256q][256c] bf16; zero stats ----------
__global__ __launch_bounds__(256) void transposeD(
    const float* __restrict__ x, unsigned short* __restrict__ y, float* __restrict__ stats) {
    __shared__ float tile[32][33];
    int b  = blockIdx.z;
    int p0 = blockIdx.x * 32;      // q tile
    int c0 = blockIdx.y * 32;      // c tile
    const float* xb = x + (size_t)b * 256 * 256;
    unsigned short* yb = y + (size_t)b * 256 * 256;
    int tx = threadIdx.x, ty = threadIdx.y;
    #pragma unroll
    for (int i = 0; i < 32; i += 8)
        tile[ty + i][tx] = xb[(size_t)(c0 + ty + i) * 256 + (p0 + tx)];
    __syncthreads();
    int tid = ty * 32 + tx;
    #pragma unroll
    for (int k = 0; k < 2; ++k) {
        int wi = tid * 2 + k;          // 0..511
        int pl = wi >> 4;              // local q row
        int cp = wi & 15;              // c-pair
        unsigned short lo = f2bf(tile[2 * cp][pl]);
        unsigned short hi = f2bf(tile[2 * cp + 1][pl]);
        unsigned int packed = (unsigned int)lo | ((unsigned int)hi << 16);
        *reinterpret_cast<unsigned int*>(&yb[(size_t)(p0 + pl) * 256 + (c0 + 2 * cp)]) = packed;
    }
    if (blockIdx.x == 0 && blockIdx.y == 0 && blockIdx.z == 0 && tid == 0) {
        stats[0] = 0.f;
        stats[1] = 0.f;
    }
}

// ---------- fused conv: stage S->LDS(bf16,swizzled), GEMM vs Dt, partials to P ----------
// Block = (b, image row r). Computes G[p=r*64 .. r*64+64)[q=0..256) and writes
// 16-tap diagonal sums NON-ATOMICALLY to P[b][r][i][x].
//
// LDS A layout (bf16, XOR-swizzled for conflict-free ds_read_b128 / ds_write_b64):
//   byte(p, c) = p*512 + (((c>>3) ^ (p&15) ^ (p>>4)) << 4) + (c&7)*2
// Epilogue layout gtT[q][p]: stride 68 bf16 -> b64 dump writes, gather reads rows.
//
// Register budget (no-spill proof): staging peak = v[4][4](64) + bcur(16) + addr(~12) ~ 92;
// GEMM peak = acc(64) + bcur(16) + af(16) + addr(~12) ~ 108.  Cap at launch_bounds(256,4)=128.
__global__ __launch_bounds__(256, 4) void conv_fused(
    const float* __restrict__ S,             // [16][256][64][64] f32
    const unsigned short* __restrict__ Dt,   // [16][256q][256c] bf16
    float* __restrict__ P) {                 // [16][64][16][52] f32 partials
    // union: At swizzled bf16 (32768 B)  /  gtT bf16 [256][68] (34816 B)
    __shared__ __align__(16) char lds[256 * 68 * 2];
    char* base = lds;

    int b = blockIdx.x >> 6;
    int r = blockIdx.x & 63;
    int tid = threadIdx.x;

    int w    = tid >> 6;          // wave 0..3
    int lane = tid & 63;
    int m    = lane & 15;
    int kg   = lane >> 4;
    const unsigned short* Db = Dt + ((size_t)(b * 256 + 64 * w)) * 256;

    // ---- stage: issue ALL 16 global loads ----
    // thread t: px = t&15 (p-group 4*px..4*px+3), cq = t>>4 (c-group 4*cq..4*cq+3 per round)
    int px = tid & 15;
    int cq = tid >> 4;
    const float* Sbr = S + ((size_t)b * 256 * 64 + r) * 64;   // + c*4096 + p

    f32x4 v[4][4];
    #pragma unroll
    for (int rho = 0; rho < 4; ++rho) {
        int c0 = rho * 64 + 4 * cq;
        #pragma unroll
        for (int j = 0; j < 4; ++j)
            v[rho][j] = *reinterpret_cast<const f32x4*>(Sbr + (size_t)(c0 + j) * 4096 + 4 * px);
    }
    // prefetch B for K-step 0 (stays in flight across the lgkm-only barrier)
    bf16x8 bcur[4];
    #pragma unroll
    for (int n = 0; n < 4; ++n)
        bcur[n] = *reinterpret_cast<const bf16x8*>(Db + (size_t)(16 * n + m) * 256 + kg * 8);
    __builtin_amdgcn_sched_barrier(0);   // keep all loads issued before any consumption

    // convert + in-register 4x4 transpose + ds_write_b64
    #pragma unroll
    for (int rho = 0; rho < 4; ++rho) {
        int slot = 8 * rho + (cq >> 1);
        int half = cq & 1;
        #pragma unroll
        for (int e = 0; e < 4; ++e) {
            int p = 4 * px + e;
            int swz = (p & 15) ^ (p >> 4);
            ushort4 o;
            o.x = f2bf(v[rho][0][e]);
            o.y = f2bf(v[rho][1][e]);
            o.z = f2bf(v[rho][2][e]);
            o.w = f2bf(v[rho][3][e]);
            *reinterpret_cast<ushort4*>(base + p * 512 + ((slot ^ swz) << 4) + half * 8) = o;
        }
    }
    // barrier that waits only for LDS writes; B-prefetch (vmcnt) stays in flight
    asm volatile("s_waitcnt lgkmcnt(0)" ::: "memory");
    __builtin_amdgcn_s_barrier();

    // ---- GEMM: wave w computes q in [64w, 64w+64), all 64 p rows, K=256 ----
    f32x4 acc[4][4];
    #pragma unroll
    for (int i = 0; i < 4; ++i)
        #pragma unroll
        for (int j = 0; j < 4; ++j)
            acc[i][j] = f32x4{0.f, 0.f, 0.f, 0.f};

    #pragma unroll
    for (int step = 0; step < 8; ++step) {
        bf16x8 af[4];
        #pragma unroll
        for (int pa = 0; pa < 4; ++pa) {
            int p = 16 * pa + m;
            int slot = (4 * step + kg) ^ m ^ pa;     // (c>>3) ^ (p&15) ^ (p>>4)
            af[pa] = *reinterpret_cast<const bf16x8*>(base + p * 512 + (slot << 4));
        }
        #pragma unroll
        for (int pa = 0; pa < 4; ++pa)
            #pragma unroll
            for (int n = 0; n < 4; ++n)
                acc[pa][n] = __builtin_amdgcn_mfma_f32_16x16x32_bf16(af[pa], bcur[n], acc[pa][n], 0, 0, 0);
        // single-buffer rotate: load next step's B after this step's MFMAs consume bcur
        if (step < 7) {
            #pragma unroll
            for (int n = 0; n < 4; ++n)
                bcur[n] = *reinterpret_cast<const bf16x8*>(
                    Db + (size_t)(16 * n + m) * 256 + (step + 1) * 32 + kg * 8);
        }
    }

    __syncthreads();   // all waves done reading At before overwrite

    // ---- dump G tile to LDS as bf16: gtT[q][p], stride 68, b64-packed writes ----
    unsigned short* gt = (unsigned short*)base;
    #pragma unroll
    for (int pa = 0; pa < 4; ++pa) {
        int p0 = 16 * pa + 4 * kg;
        #pragma unroll
        for (int n = 0; n < 4; ++n) {
            int q = 64 * w + 16 * n + m;
            ushort4 o;
            o.x = f2bf(acc[pa][n][0]);
            o.y = f2bf(acc[pa][n][1]);
            o.z = f2bf(acc[pa][n][2]);
            o.w = f2bf(acc[pa][n][3]);
            *reinterpret_cast<ushort4*>(&gt[q * 68 + p0]) = o;
        }
    }
    __syncthreads();

    // ---- partials: P[b][r][i][x] = sum_j G[x+j][16i+j] = sum_j gtT[16i+j][x+j] ----
    int ilo = (r > 48) ? (r - 48) : 0;
    int ihi = (r < 15) ? r : 15;
    int total = (ihi - ilo + 1) * 49;
    for (int o = tid; o < total; o += 256) {
        int i = ilo + o / 49;
        int x = o % 49;
        float s = 0.f;
        int qb = 16 * i;
        #pragma unroll
        for (int j = 0; j < 16; ++j)
            s += bf2f(gt[(qb + j) * 68 + (x + j)]);
        P[((size_t)((b * 64 + r) * 16 + i)) * 52 + x] = s;
    }
}

// ---------- reduce partials + global stats: mm[b][y][x] = sum_i P[b][y+i][i][x] ----------
__global__ __launch_bounds__(256) void reduce_kernel(
    const float* __restrict__ P, float* __restrict__ mm, float* __restrict__ stats) {
    int idx = blockIdx.x * 256 + threadIdx.x;
    float s = 0.f;
    if (idx < 38416) {
        int b  = idx / 2401;
        int yx = idx % 2401;
        int y  = yx / 49;
        int x  = yx % 49;
        #pragma unroll
        for (int i = 0; i < 16; ++i)
            s += P[((size_t)((b * 64 + y + i) * 16 + i)) * 52 + x];
        mm[idx] = s;
    }
    // block-reduce (sum, sumsq), one atomic pair per block
    __shared__ float rs[256];
    __shared__ float rq[256];
    int tid = threadIdx.x;
    rs[tid] = (idx < 38416) ? s : 0.f;
    rq[tid] = (idx < 38416) ? s * s : 0.f;
    __syncthreads();
    for (int st = 128; st > 0; st >>= 1) {
        if (tid < st) { rs[tid] += rs[tid + st]; rq[tid] += rq[tid + st]; }
        __syncthreads();
    }
    if (tid == 0) {
        atomicAdd(&stats[0], rs[0]);
        atomicAdd(&stats[1], rq[0]);
    }
}

// ---------- fallback naive conv (tiny ws) ----------
__global__ __launch_bounds__(256) void conv_naive(
    const float* __restrict__ S, const float* __restrict__ D, float* __restrict__ mm) {
    int blk = blockIdx.x;            // b*2401 + y*49 + x
    int b = blk / 2401;
    int yx = blk % 2401;
    int y = yx / 49, x = yx % 49;
    int c = threadIdx.x;
    const float* Sp = S + (((size_t)b * 256 + c) * 64 + y) * 64 + x;
    const float* Dp = D + ((size_t)b * 256 + c) * 256;
    float s = 0.f;
    #pragma unroll
    for (int i = 0; i < 16; ++i)
        #pragma unroll 4
        for (int j = 0; j < 16; ++j)
            s += Sp[i * 64 + j] * Dp[i * 16 + j];
    __shared__ float red[256];
    red[c] = s;
    __syncthreads();
    for (int st = 128; st > 0; st >>= 1) {
        if (c < st) red[c] += red[c + st];
        __syncthreads();
    }
    if (c == 0) mm[blk] = red[0];
}

// ---------- fallback stats: raw sums over 38416 values ----------
__global__ __launch_bounds__(1024) void stats_kernel(
    const float* __restrict__ mm, float* __restrict__ stats) {
    __shared__ float ssum[1024];
    __shared__ float ssq[1024];
    int tid = threadIdx.x;
    float s = 0.f, q = 0.f;
    for (int i = tid; i < 38416; i += 1024) {
        float v = mm[i];
        s += v; q += v * v;
    }
    ssum[tid] = s; ssq[tid] = q;
    __syncthreads();
    for (int st = 512; st > 0; st >>= 1) {
        if (tid < st) { ssum[tid] += ssum[tid + st]; ssq[tid] += ssq[tid + st]; }
        __syncthreads();
    }
    if (tid == 0) {
        stats[0] = ssum[0];
        stats[1] = ssq[0];
    }
}

// ---------- normalize + bilinear 49x49 -> 256x256 (stats are raw sums) ----------
__global__ __launch_bounds__(256) void bilinear_kernel(
    const float* __restrict__ mm, const float* __restrict__ stats,
    const float* __restrict__ gamma, const float* __restrict__ beta,
    float* __restrict__ out) {
    int idx = blockIdx.x * 256 + threadIdx.x;   // 16*256*256 = 1,048,576
    int b  = idx >> 16;
    int oy = (idx >> 8) & 255;
    int ox = idx & 255;
    const float scale = 49.0f / 256.0f;
    float cy = fminf(fmaxf((oy + 0.5f) * scale - 0.5f, 0.0f), 48.0f);
    int y0 = (int)cy; int y1 = min(y0 + 1, 48); float wy = cy - (float)y0;
    float cx = fminf(fmaxf((ox + 0.5f) * scale - 0.5f, 0.0f), 48.0f);
    int x0 = (int)cx; int x1 = min(x0 + 1, 48); float wx = cx - (float)x0;
    const float* mb = mm + (size_t)b * 2401;
    float v00 = mb[y0 * 49 + x0];
    float v01 = mb[y0 * 49 + x1];
    float v10 = mb[y1 * 49 + x0];
    float v11 = mb[y1 * 49 + x1];
    float r0 = v00 * (1.f - wy) + v10 * wy;
    float r1 = v01 * (1.f - wy) + v11 * wy;
    float v  = r0 * (1.f - wx) + r1 * wx;
    const float invN = 1.0f / 38416.0f;
    float mean = stats[0] * invN;
    float var  = stats[1] * invN - mean * mean;
    float rstd = rsqrtf(var + 1e-5f);
    v = (v - mean) * rstd * gamma[0] + beta[0];
    out[idx] = v;
}

extern "C" void kernel_launch(void* const* d_in, const int* in_sizes, int n_in,
                              void* d_out, int out_size, void* d_ws, size_t ws_size,
                              hipStream_t stream) {
    const float* S     = (const float*)d_in[0];   // (16,256,64,64)
    const float* D     = (const float*)d_in[1];   // (16,256,16,16)
    const float* gamma = (const float*)d_in[2];   // (1,)
    const float* beta  = (const float*)d_in[3];   // (1,)
    float* out = (float*)d_out;                   // (16,1,256,256)

    char* ws = (char*)d_ws;
    const size_t sizeDt = (size_t)16 * 256 * 256 * 2;        // 2,097,152
    const size_t sizeMm = (size_t)38416 * 4;                 //   153,664
    const size_t sizeP  = (size_t)16 * 64 * 16 * 52 * 4;     // 3,407,872
    const size_t offDt = 0;
    const size_t offMm = offDt + sizeDt;
    const size_t offStats = offMm + sizeMm;
    const size_t offP = (offStats + 2 * sizeof(float) + 255) & ~(size_t)255;
    const size_t needFast = offP + sizeP;

    bool fast = (ws_size >= needFast);
    float* mm;
    float* stats;
    if (fast) {
        mm    = (float*)(ws + offMm);
        stats = (float*)(ws + offStats);
    } else {
        mm    = (float*)ws;
        stats = (float*)(ws + sizeMm);
    }

    if (fast) {
        unsigned short* Dt = (unsigned short*)(ws + offDt);
        float* P = (float*)(ws + offP);
        transposeD<<<dim3(8, 8, 16), dim3(32, 8), 0, stream>>>(D, Dt, stats);
        // PROBE: conv launched twice (idempotent — each block overwrites its own
        // P slice). Marginal time of launch #2 = conv's standalone warm duration.
        conv_fused<<<1024, 256, 0, stream>>>(S, Dt, P);
        conv_fused<<<1024, 256, 0, stream>>>(S, Dt, P);
        reduce_kernel<<<151, 256, 0, stream>>>(P, mm, stats);
    } else {
        conv_naive<<<16 * 2401, 256, 0, stream>>>(S, D, mm);
        stats_kernel<<<1, 1024, 0, stream>>>(mm, stats);
    }
    bilinear_kernel<<<4096, 256, 0, stream>>>(mm, stats, gamma, beta, out);
}

// Round 7
// 62.901 us; speedup vs baseline: 1.0595x; 1.0595x over previous
//
#include <hip/hip_runtime.h>

// ---------- types ----------
using f32x4  = __attribute__((ext_vector_type(4))) float;
using bf16x8 = __attribute__((ext_vector_type(8))) short;            // 8 bf16
using u16x8  = __attribute__((ext_vector_type(8))) unsigned short;   // 16 B

__device__ __forceinline__ unsigned short f2bf(float f) {
    union { float f; unsigned int u; } v; v.f = f;
    unsigned int r = v.u + 0x7fffu + ((v.u >> 16) & 1u);  // RNE
    return (unsigned short)(r >> 16);
}

__device__ __forceinline__ float bf2f(unsigned short u) {
    union { unsigned int u; float f; } v; v.u = ((unsigned int)u) << 16;
    return v.f;
}

__device__ __forceinline__ void gload_lds16(const void* g, void* l) {
    __builtin_amdgcn_global_load_lds(
        (const __attribute__((address_space(1))) unsigned int*)g,
        (__attribute__((address_space(3))) unsigned int*)l,
        16, 0, 0);
}

// ---------- transpose D [16][256c][256q] f32 -> Dt [16][256q][256c] bf16; zero stats ----------
__global__ __launch_bounds__(256) void transposeD(
    const float* __restrict__ x, unsigned short* __restrict__ y, float* __restrict__ stats) {
    __shared__ float tile[32][33];
    int b  = blockIdx.z;
    int p0 = blockIdx.x * 32;      // q tile
    int c0 = blockIdx.y * 32;      // c tile
    const float* xb = x + (size_t)b * 256 * 256;
    unsigned short* yb = y + (size_t)b * 256 * 256;
    int tx = threadIdx.x, ty = threadIdx.y;
    #pragma unroll
    for (int i = 0; i < 32; i += 8)
        tile[ty + i][tx] = xb[(size_t)(c0 + ty + i) * 256 + (p0 + tx)];
    __syncthreads();
    int tid = ty * 32 + tx;
    #pragma unroll
    for (int k = 0; k < 2; ++k) {
        int wi = tid * 2 + k;          // 0..511
        int pl = wi >> 4;              // local q row
        int cp = wi & 15;              // c-pair
        unsigned short lo = f2bf(tile[2 * cp][pl]);
        unsigned short hi = f2bf(tile[2 * cp + 1][pl]);
        unsigned int packed = (unsigned int)lo | ((unsigned int)hi << 16);
        *reinterpret_cast<unsigned int*>(&yb[(size_t)(p0 + pl) * 256 + (c0 + 2 * cp)]) = packed;
    }
    if (blockIdx.x == 0 && blockIdx.y == 0 && blockIdx.z == 0 && tid == 0) {
        stats[0] = 0.f;
        stats[1] = 0.f;
    }
}

// ---------- transpose S -> pre-swizzled LDS images ----------
// St[b][r] is a 32 KB image: byte(x, c) = x*512 + (((c>>3) ^ (x&15) ^ (x>>4)) << 4) + (c&7)*2
// Block = (b, cg=c-group of 16, rh=row half). Reads 16 contiguous c-planes (rows rh*32..+31),
// writes the c-slice of 32 images. Block-id mapping groups the 4 cg sharing each 128B output
// line onto the same XCD (id mod 8) for L2 write-merge.
__global__ __launch_bounds__(256, 2) void transposeS(
    const float* __restrict__ S, unsigned short* __restrict__ St) {
    __shared__ float tile[16 * 273 + 16];   // t(cc,j,x) = cc*273 + j*68 + x

    int id  = blockIdx.x;          // 0..511
    int u   = id >> 7;             // cg & 3
    int rem = id & 127;
    int b   = rem >> 3;
    int q   = (rem >> 1) & 3;      // cg >> 2
    int rh  = rem & 1;
    int cg  = 4 * q + u;

    int tid = threadIdx.x;
    int cc  = tid >> 4;            // 0..15 (read role: plane within group)
    int px  = tid & 15;
    int rj  = tid >> 6;            // 0..3  (write role: row within iter)
    int xx  = tid & 63;            // 0..63 (write role: x)
    int swz = (xx & 15) ^ (xx >> 4);
    int es  = (2 * cg) ^ swz;      // chunk slot for h=0

    const float* Sp = S + ((size_t)(b * 256 + 16 * cg + cc)) * 4096;     // plane base
    unsigned short* Stb = St + ((size_t)(b * 64)) * 16384;               // images (shorts)

    f32x4 cur[4], nxt[4];
    int rbase = rh * 32;
    #pragma unroll
    for (int j = 0; j < 4; ++j)
        cur[j] = *reinterpret_cast<const f32x4*>(Sp + (size_t)(rbase + j) * 64 + 4 * px);

    for (int it = 0; it < 8; ++it) {
        int r0 = rbase + it * 4;
        if (it < 7) {
            #pragma unroll
            for (int j = 0; j < 4; ++j)
                nxt[j] = *reinterpret_cast<const f32x4*>(Sp + (size_t)(r0 + 4 + j) * 64 + 4 * px);
        }
        #pragma unroll
        for (int j = 0; j < 4; ++j)
            #pragma unroll
            for (int e = 0; e < 4; ++e)
                tile[cc * 273 + j * 68 + 4 * px + e] = cur[j][e];
        __syncthreads();

        // write: thread (rj, xx) emits 2 x 16B chunks (c = 16cg+8h+0..7)
        unsigned short* dst = Stb + (size_t)(r0 + rj) * 16384 + xx * 256;
        #pragma unroll
        for (int h = 0; h < 2; ++h) {
            u16x8 o;
            #pragma unroll
            for (int cj = 0; cj < 8; ++cj)
                o[cj] = f2bf(tile[(8 * h + cj) * 273 + rj * 68 + xx]);
            *reinterpret_cast<u16x8*>(dst + ((es ^ h) << 3)) = o;
        }
        __syncthreads();
        #pragma unroll
        for (int j = 0; j < 4; ++j)
            cur[j] = nxt[j];
    }
}

// ---------- fused conv: async-load pre-swizzled A image, GEMM vs Dt, partials to P ----------
__global__ __launch_bounds__(256, 4) void conv_fused(
    const unsigned short* __restrict__ St,   // [16][64] x 32 KB pre-swizzled images
    const unsigned short* __restrict__ Dt,   // [16][256q][256c] bf16
    float* __restrict__ P) {                 // [16][64][16][52] f32 partials
    // union: At swizzled bf16 (32768 B)  /  gtT bf16 [256][68] (34816 B)
    __shared__ __align__(16) char lds[256 * 68 * 2];
    char* base = lds;

    int b = blockIdx.x >> 6;
    int r = blockIdx.x & 63;
    int tid = threadIdx.x;

    int w    = tid >> 6;          // wave 0..3
    int lane = tid & 63;
    int m    = lane & 15;
    int kg   = lane >> 4;

    // ---- stage A: one contiguous 32 KB async burst (image already swizzled) ----
    const char* Sb = reinterpret_cast<const char*>(St) + (((size_t)(b * 64 + r)) << 15);
    #pragma unroll
    for (int it = 0; it < 8; ++it)
        gload_lds16(Sb + it * 4096 + tid * 16, base + it * 4096 + tid * 16);

    const unsigned short* Db = Dt + ((size_t)(b * 256 + 64 * w)) * 256;
    bf16x8 bcur[4];
    #pragma unroll
    for (int n = 0; n < 4; ++n)
        bcur[n] = *reinterpret_cast<const bf16x8*>(Db + (size_t)(16 * n + m) * 256 + kg * 8);

    __syncthreads();   // drains vmcnt (async LDS writes + bcur) before use

    // ---- GEMM: wave w computes q in [64w, 64w+64), all 64 p rows, K=256 ----
    f32x4 acc[4][4];
    #pragma unroll
    for (int i = 0; i < 4; ++i)
        #pragma unroll
        for (int j = 0; j < 4; ++j)
            acc[i][j] = f32x4{0.f, 0.f, 0.f, 0.f};

    #pragma unroll
    for (int step = 0; step < 8; ++step) {
        bf16x8 af[4];
        #pragma unroll
        for (int pa = 0; pa < 4; ++pa) {
            int p = 16 * pa + m;
            int slot = (4 * step + kg) ^ m ^ pa;     // (c>>3) ^ (p&15) ^ (p>>4)
            af[pa] = *reinterpret_cast<const bf16x8*>(base + p * 512 + (slot << 4));
        }
        #pragma unroll
        for (int pa = 0; pa < 4; ++pa)
            #pragma unroll
            for (int n = 0; n < 4; ++n)
                acc[pa][n] = __builtin_amdgcn_mfma_f32_16x16x32_bf16(af[pa], bcur[n], acc[pa][n], 0, 0, 0);
        if (step < 7) {
            #pragma unroll
            for (int n = 0; n < 4; ++n)
                bcur[n] = *reinterpret_cast<const bf16x8*>(
                    Db + (size_t)(16 * n + m) * 256 + (step + 1) * 32 + kg * 8);
        }
    }

    __syncthreads();   // all waves done reading At before overwrite

    // ---- dump G tile to LDS as bf16: gtT[q][p], stride 68, b64-packed writes ----
    unsigned short* gt = (unsigned short*)base;
    #pragma unroll
    for (int pa = 0; pa < 4; ++pa) {
        int p0 = 16 * pa + 4 * kg;
        #pragma unroll
        for (int n = 0; n < 4; ++n) {
            int q = 64 * w + 16 * n + m;
            ushort4 o;
            o.x = f2bf(acc[pa][n][0]);
            o.y = f2bf(acc[pa][n][1]);
            o.z = f2bf(acc[pa][n][2]);
            o.w = f2bf(acc[pa][n][3]);
            *reinterpret_cast<ushort4*>(&gt[q * 68 + p0]) = o;
        }
    }
    __syncthreads();

    // ---- partials: P[b][r][i][x] = sum_j G[x+j][16i+j] = sum_j gtT[16i+j][x+j] ----
    int ilo = (r > 48) ? (r - 48) : 0;
    int ihi = (r < 15) ? r : 15;
    int total = (ihi - ilo + 1) * 49;
    for (int o = tid; o < total; o += 256) {
        int i = ilo + o / 49;
        int x = o % 49;
        float s = 0.f;
        int qb = 16 * i;
        #pragma unroll
        for (int j = 0; j < 16; ++j)
            s += bf2f(gt[(qb + j) * 68 + (x + j)]);
        P[((size_t)((b * 64 + r) * 16 + i)) * 52 + x] = s;
    }
}

// ---------- reduce partials + global stats: mm[b][y][x] = sum_i P[b][y+i][i][x] ----------
__global__ __launch_bounds__(256) void reduce_kernel(
    const float* __restrict__ P, float* __restrict__ mm, float* __restrict__ stats) {
    int idx = blockIdx.x * 256 + threadIdx.x;
    float s = 0.f;
    if (idx < 38416) {
        int b  = idx / 2401;
        int yx = idx % 2401;
        int y  = yx / 49;
        int x  = yx % 49;
        #pragma unroll
        for (int i = 0; i < 16; ++i)
            s += P[((size_t)((b * 64 + y + i) * 16 + i)) * 52 + x];
        mm[idx] = s;
    }
    __shared__ float rs[256];
    __shared__ float rq[256];
    int tid = threadIdx.x;
    rs[tid] = (idx < 38416) ? s : 0.f;
    rq[tid] = (idx < 38416) ? s * s : 0.f;
    __syncthreads();
    for (int st = 128; st > 0; st >>= 1) {
        if (tid < st) { rs[tid] += rs[tid + st]; rq[tid] += rq[tid + st]; }
        __syncthreads();
    }
    if (tid == 0) {
        atomicAdd(&stats[0], rs[0]);
        atomicAdd(&stats[1], rq[0]);
    }
}

// ---------- fallback naive conv (tiny ws) ----------
__global__ __launch_bounds__(256) void conv_naive(
    const float* __restrict__ S, const float* __restrict__ D, float* __restrict__ mm) {
    int blk = blockIdx.x;            // b*2401 + y*49 + x
    int b = blk / 2401;
    int yx = blk % 2401;
    int y = yx / 49, x = yx % 49;
    int c = threadIdx.x;
    const float* Sp = S + (((size_t)b * 256 + c) * 64 + y) * 64 + x;
    const float* Dp = D + ((size_t)b * 256 + c) * 256;
    float s = 0.f;
    #pragma unroll
    for (int i = 0; i < 16; ++i)
        #pragma unroll 4
        for (int j = 0; j < 16; ++j)
            s += Sp[i * 64 + j] * Dp[i * 16 + j];
    __shared__ float red[256];
    red[c] = s;
    __syncthreads();
    for (int st = 128; st > 0; st >>= 1) {
        if (c < st) red[c] += red[c + st];
        __syncthreads();
    }
    if (c == 0) mm[blk] = red[0];
}

// ---------- fallback stats: raw sums over 38416 values ----------
__global__ __launch_bounds__(1024) void stats_kernel(
    const float* __restrict__ mm, float* __restrict__ stats) {
    __shared__ float ssum[1024];
    __shared__ float ssq[1024];
    int tid = threadIdx.x;
    float s = 0.f, q = 0.f;
    for (int i = tid; i < 38416; i += 1024) {
        float v = mm[i];
        s += v; q += v * v;
    }
    ssum[tid] = s; ssq[tid] = q;
    __syncthreads();
    for (int st = 512; st > 0; st >>= 1) {
        if (tid < st) { ssum[tid] += ssum[tid + st]; ssq[tid] += ssq[tid + st]; }
        __syncthreads();
    }
    if (tid == 0) {
        stats[0] = ssum[0];
        stats[1] = ssq[0];
    }
}

// ---------- normalize + bilinear 49x49 -> 256x256 (stats are raw sums) ----------
__global__ __launch_bounds__(256) void bilinear_kernel(
    const float* __restrict__ mm, const float* __restrict__ stats,
    const float* __restrict__ gamma, const float* __restrict__ beta,
    float* __restrict__ out) {
    int idx = blockIdx.x * 256 + threadIdx.x;   // 16*256*256 = 1,048,576
    int b  = idx >> 16;
    int oy = (idx >> 8) & 255;
    int ox = idx & 255;
    const float scale = 49.0f / 256.0f;
    float cy = fminf(fmaxf((oy + 0.5f) * scale - 0.5f, 0.0f), 48.0f);
    int y0 = (int)cy; int y1 = min(y0 + 1, 48); float wy = cy - (float)y0;
    float cx = fminf(fmaxf((ox + 0.5f) * scale - 0.5f, 0.0f), 48.0f);
    int x0 = (int)cx; int x1 = min(x0 + 1, 48); float wx = cx - (float)x0;
    const float* mb = mm + (size_t)b * 2401;
    float v00 = mb[y0 * 49 + x0];
    float v01 = mb[y0 * 49 + x1];
    float v10 = mb[y1 * 49 + x0];
    float v11 = mb[y1 * 49 + x1];
    float r0 = v00 * (1.f - wy) + v10 * wy;
    float r1 = v01 * (1.f - wy) + v11 * wy;
    float v  = r0 * (1.f - wx) + r1 * wx;
    const float invN = 1.0f / 38416.0f;
    float mean = stats[0] * invN;
    float var  = stats[1] * invN - mean * mean;
    float rstd = rsqrtf(var + 1e-5f);
    v = (v - mean) * rstd * gamma[0] + beta[0];
    out[idx] = v;
}

extern "C" void kernel_launch(void* const* d_in, const int* in_sizes, int n_in,
                              void* d_out, int out_size, void* d_ws, size_t ws_size,
                              hipStream_t stream) {
    const float* S     = (const float*)d_in[0];   // (16,256,64,64)
    const float* D     = (const float*)d_in[1];   // (16,256,16,16)
    const float* gamma = (const float*)d_in[2];   // (1,)
    const float* beta  = (const float*)d_in[3];   // (1,)
    float* out = (float*)d_out;                   // (16,1,256,256)

    char* ws = (char*)d_ws;
    const size_t sizeDt = (size_t)16 * 256 * 256 * 2;        //  2,097,152
    const size_t sizeMm = (size_t)38416 * 4;                 //    153,664
    const size_t sizeP  = (size_t)16 * 64 * 16 * 52 * 4;     //  3,407,872
    const size_t sizeSt = (size_t)16 * 64 * 32768;           // 33,554,432
    const size_t offDt = 0;
    const size_t offMm = offDt + sizeDt;
    const size_t offStats = offMm + sizeMm;
    const size_t offP = (offStats + 2 * sizeof(float) + 255) & ~(size_t)255;
    const size_t offSt = offP + sizeP;
    const size_t needFast = offSt + sizeSt;

    bool fast = (ws_size >= needFast);
    float* mm;
    float* stats;
    if (fast) {
        mm    = (float*)(ws + offMm);
        stats = (float*)(ws + offStats);
    } else {
        mm    = (float*)ws;
        stats = (float*)(ws + sizeMm);
    }

    if (fast) {
        unsigned short* Dt = (unsigned short*)(ws + offDt);
        float* P = (float*)(ws + offP);
        unsigned short* St = (unsigned short*)(ws + offSt);
        transposeD<<<dim3(8, 8, 16), dim3(32, 8), 0, stream>>>(D, Dt, stats);
        transposeS<<<512, 256, 0, stream>>>(S, St);
        conv_fused<<<1024, 256, 0, stream>>>(St, Dt, P);
        reduce_kernel<<<151, 256, 0, stream>>>(P, mm, stats);
    } else {
        conv_naive<<<16 * 2401, 256, 0, stream>>>(S, D, mm);
        stats_kernel<<<1, 1024, 0, stream>>>(mm, stats);
    }
    bilinear_kernel<<<4096, 256, 0, stream>>>(mm, stats, gamma, beta, out);
}

// Round 8
// 56.810 us; speedup vs baseline: 1.1731x; 1.1072x over previous
//
#include <hip/hip_runtime.h>

// ---------- types ----------
using f32x4  = __attribute__((ext_vector_type(4))) float;
using bf16x8 = __attribute__((ext_vector_type(8))) short;            // 8 bf16
using u16x8  = __attribute__((ext_vector_type(8))) unsigned short;   // 16 B

__device__ __forceinline__ unsigned short f2bf(float f) {
    union { float f; unsigned int u; } v; v.f = f;
    unsigned int r = v.u + 0x7fffu + ((v.u >> 16) & 1u);  // RNE
    return (unsigned short)(r >> 16);
}

__device__ __forceinline__ float bf2f(unsigned short u) {
    union { unsigned int u; float f; } v; v.u = ((unsigned int)u) << 16;
    return v.f;
}

// Intermediate I: 16 b x 32 s slabs; slab = 64 r x 1KB (+1KB skew pad).
// chunk(b,s,r) channel index = 4*(s+r) mod 64 -> full channel coverage per (b,r) gather.
#define SLAB_BYTES 66560   // 64*1024 + 1024 skew

// ---------- transpose D [16][256c][256q] f32 -> Dt [16][256q][256c] bf16; zero stats ----------
__global__ __launch_bounds__(256) void transposeD(
    const float* __restrict__ x, unsigned short* __restrict__ y, float* __restrict__ stats) {
    __shared__ float tile[32][33];
    int b  = blockIdx.z;
    int p0 = blockIdx.x * 32;      // q tile
    int c0 = blockIdx.y * 32;      // c tile
    const float* xb = x + (size_t)b * 256 * 256;
    unsigned short* yb = y + (size_t)b * 256 * 256;
    int tx = threadIdx.x, ty = threadIdx.y;
    #pragma unroll
    for (int i = 0; i < 32; i += 8)
        tile[ty + i][tx] = xb[(size_t)(c0 + ty + i) * 256 + (p0 + tx)];
    __syncthreads();
    int tid = ty * 32 + tx;
    #pragma unroll
    for (int k = 0; k < 2; ++k) {
        int wi = tid * 2 + k;          // 0..511
        int pl = wi >> 4;              // local q row
        int cp = wi & 15;              // c-pair
        unsigned short lo = f2bf(tile[2 * cp][pl]);
        unsigned short hi = f2bf(tile[2 * cp + 1][pl]);
        unsigned int packed = (unsigned int)lo | ((unsigned int)hi << 16);
        *reinterpret_cast<unsigned int*>(&yb[(size_t)(p0 + pl) * 256 + (c0 + 2 * cp)]) = packed;
    }
    if (blockIdx.x == 0 && blockIdx.y == 0 && blockIdx.z == 0 && tid == 0) {
        stats[0] = 0.f;
        stats[1] = 0.f;
    }
}

// ---------- T1: S -> I. Block (b, s=c-oct 0..31): reads 8 whole planes (128KB contiguous),
// writes slab (b,s) = [r=64][x=64][cc=8] bf16 as one contiguous 64KB run. ----------
__global__ __launch_bounds__(256, 2) void transposeS1(
    const float* __restrict__ S, char* __restrict__ I) {
    __shared__ __align__(16) unsigned short tile[64 * 520];   // [r]*520 + x*8 + cc  (66560 B)

    int blk = blockIdx.x;        // 0..511
    int b = blk >> 5;
    int s = blk & 31;
    int tid = threadIdx.x;

    const float* Sp = S + ((size_t)(b * 256 + 8 * s)) * 4096;

    // stage: idx = k*256+tid -> (r = idx>>4, xq = idx&15); 8 plane-strided f32x4 loads
    #pragma unroll 2
    for (int k = 0; k < 4; ++k) {
        int idx = k * 256 + tid;
        int r = idx >> 4, xq = idx & 15;
        f32x4 v[8];
        #pragma unroll
        for (int cc = 0; cc < 8; ++cc)
            v[cc] = *reinterpret_cast<const f32x4*>(Sp + (size_t)cc * 4096 + r * 64 + xq * 4);
        #pragma unroll
        for (int e = 0; e < 4; ++e) {
            u16x8 o;
            #pragma unroll
            for (int cc = 0; cc < 8; ++cc) o[cc] = f2bf(v[cc][e]);
            *reinterpret_cast<u16x8*>(&tile[r * 520 + (xq * 4 + e) * 8]) = o;
        }
    }
    __syncthreads();

    // write: g = k*256+tid -> (r = g>>6, x = g&63); contiguous 16B pieces
    char* slab = I + ((size_t)(b * 32 + s)) * SLAB_BYTES;
    #pragma unroll 4
    for (int k = 0; k < 16; ++k) {
        int g = k * 256 + tid;
        int r = g >> 6, x = g & 63;
        u16x8 o = *reinterpret_cast<const u16x8*>(&tile[r * 520 + x * 8]);
        *reinterpret_cast<u16x8*>(slab + (size_t)r * 1024 + x * 16) = o;
    }
}

// ---------- fused conv: gather channel-spread chunks -> swizzled LDS image, GEMM, partials ----------
// LDS image: byte(p, c) = p*512 + (((c>>3) ^ (p&15) ^ (p>>4)) << 4) + (c&7)*2
__global__ __launch_bounds__(256, 4) void conv_fused(
    const char* __restrict__ I,              // slabs
    const unsigned short* __restrict__ Dt,   // [16][256q][256c] bf16
    float* __restrict__ P) {                 // [16][64][16][52] f32 partials
    // union: image (32768 B) / gtT bf16 [256][68] (34816 B)
    __shared__ __align__(16) char lds[256 * 68 * 2];
    char* base = lds;

    int b = blockIdx.x >> 6;
    int r = blockIdx.x & 63;
    int tid = threadIdx.x;

    int w    = tid >> 6;          // wave 0..3
    int lane = tid & 63;
    int m    = lane & 15;
    int kg   = lane >> 4;

    // ---- stage: 8 pieces/thread; per wave-inst: 1KB contiguous from slab (s = k*4+w) ----
    const char* Ib = I + (size_t)(b * 32) * SLAB_BYTES + (size_t)r * 1024;
    u16x8 pc[8];
    #pragma unroll
    for (int k = 0; k < 8; ++k) {
        int g = k * 256 + tid;
        int s = g >> 6, x = g & 63;
        pc[k] = *reinterpret_cast<const u16x8*>(Ib + (size_t)s * SLAB_BYTES + x * 16);
    }
    const unsigned short* Db = Dt + ((size_t)(b * 256 + 64 * w)) * 256;
    bf16x8 bcur[4];
    #pragma unroll
    for (int n = 0; n < 4; ++n)
        bcur[n] = *reinterpret_cast<const bf16x8*>(Db + (size_t)(16 * n + m) * 256 + kg * 8);
    __builtin_amdgcn_sched_barrier(0);   // all loads issued before any consumption

    #pragma unroll
    for (int k = 0; k < 8; ++k) {
        int g = k * 256 + tid;
        int s = g >> 6, x = g & 63;
        int slot = s ^ ((x & 15) ^ (x >> 4));
        *reinterpret_cast<u16x8*>(base + x * 512 + slot * 16) = pc[k];
    }
    // barrier waiting only on LDS writes; bcur global loads stay in flight
    asm volatile("s_waitcnt lgkmcnt(0)" ::: "memory");
    __builtin_amdgcn_s_barrier();

    // ---- GEMM: wave w computes q in [64w, 64w+64), all 64 p rows, K=256 ----
    f32x4 acc[4][4];
    #pragma unroll
    for (int i = 0; i < 4; ++i)
        #pragma unroll
        for (int j = 0; j < 4; ++j)
            acc[i][j] = f32x4{0.f, 0.f, 0.f, 0.f};

    #pragma unroll
    for (int step = 0; step < 8; ++step) {
        bf16x8 af[4];
        #pragma unroll
        for (int pa = 0; pa < 4; ++pa) {
            int p = 16 * pa + m;
            int slot = (4 * step + kg) ^ m ^ pa;     // (c>>3) ^ (p&15) ^ (p>>4)
            af[pa] = *reinterpret_cast<const bf16x8*>(base + p * 512 + (slot << 4));
        }
        #pragma unroll
        for (int pa = 0; pa < 4; ++pa)
            #pragma unroll
            for (int n = 0; n < 4; ++n)
                acc[pa][n] = __builtin_amdgcn_mfma_f32_16x16x32_bf16(af[pa], bcur[n], acc[pa][n], 0, 0, 0);
        if (step < 7) {
            #pragma unroll
            for (int n = 0; n < 4; ++n)
                bcur[n] = *reinterpret_cast<const bf16x8*>(
                    Db + (size_t)(16 * n + m) * 256 + (step + 1) * 32 + kg * 8);
        }
    }

    __syncthreads();   // all waves done reading image before overwrite

    // ---- dump G tile: gtT[q][p], stride 68, b64-packed writes ----
    unsigned short* gt = (unsigned short*)base;
    #pragma unroll
    for (int pa = 0; pa < 4; ++pa) {
        int p0 = 16 * pa + 4 * kg;
        #pragma unroll
        for (int n = 0; n < 4; ++n) {
            int q = 64 * w + 16 * n + m;
            ushort4 o;
            o.x = f2bf(acc[pa][n][0]);
            o.y = f2bf(acc[pa][n][1]);
            o.z = f2bf(acc[pa][n][2]);
            o.w = f2bf(acc[pa][n][3]);
            *reinterpret_cast<ushort4*>(&gt[q * 68 + p0]) = o;
        }
    }
    __syncthreads();

    // ---- partials: P[b][r][i][x] = sum_j gtT[16i+j][x+j] ----
    int ilo = (r > 48) ? (r - 48) : 0;
    int ihi = (r < 15) ? r : 15;
    int total = (ihi - ilo + 1) * 49;
    for (int o = tid; o < total; o += 256) {
        int i = ilo + o / 49;
        int x = o % 49;
        float s = 0.f;
        int qb = 16 * i;
        #pragma unroll
        for (int j = 0; j < 16; ++j)
            s += bf2f(gt[(qb + j) * 68 + (x + j)]);
        P[((size_t)((b * 64 + r) * 16 + i)) * 52 + x] = s;
    }
}

// ---------- reduce partials + global stats ----------
__global__ __launch_bounds__(256) void reduce_kernel(
    const float* __restrict__ P, float* __restrict__ mm, float* __restrict__ stats) {
    int idx = blockIdx.x * 256 + threadIdx.x;
    float s = 0.f;
    if (idx < 38416) {
        int b  = idx / 2401;
        int yx = idx % 2401;
        int y  = yx / 49;
        int x  = yx % 49;
        #pragma unroll
        for (int i = 0; i < 16; ++i)
            s += P[((size_t)((b * 64 + y + i) * 16 + i)) * 52 + x];
        mm[idx] = s;
    }
    __shared__ float rs[256];
    __shared__ float rq[256];
    int tid = threadIdx.x;
    rs[tid] = (idx < 38416) ? s : 0.f;
    rq[tid] = (idx < 38416) ? s * s : 0.f;
    __syncthreads();
    for (int st = 128; st > 0; st >>= 1) {
        if (tid < st) { rs[tid] += rs[tid + st]; rq[tid] += rq[tid + st]; }
        __syncthreads();
    }
    if (tid == 0) {
        atomicAdd(&stats[0], rs[0]);
        atomicAdd(&stats[1], rq[0]);
    }
}

// ---------- fallback naive conv (tiny ws) ----------
__global__ __launch_bounds__(256) void conv_naive(
    const float* __restrict__ S, const float* __restrict__ D, float* __restrict__ mm) {
    int blk = blockIdx.x;            // b*2401 + y*49 + x
    int b = blk / 2401;
    int yx = blk % 2401;
    int y = yx / 49, x = yx % 49;
    int c = threadIdx.x;
    const float* Sp = S + (((size_t)b * 256 + c) * 64 + y) * 64 + x;
    const float* Dp = D + ((size_t)b * 256 + c) * 256;
    float s = 0.f;
    #pragma unroll
    for (int i = 0; i < 16; ++i)
        #pragma unroll 4
        for (int j = 0; j < 16; ++j)
            s += Sp[i * 64 + j] * Dp[i * 16 + j];
    __shared__ float red[256];
    red[c] = s;
    __syncthreads();
    for (int st = 128; st > 0; st >>= 1) {
        if (c < st) red[c] += red[c + st];
        __syncthreads();
    }
    if (c == 0) mm[blk] = red[0];
}

// ---------- fallback stats: raw sums ----------
__global__ __launch_bounds__(1024) void stats_kernel(
    const float* __restrict__ mm, float* __restrict__ stats) {
    __shared__ float ssum[1024];
    __shared__ float ssq[1024];
    int tid = threadIdx.x;
    float s = 0.f, q = 0.f;
    for (int i = tid; i < 38416; i += 1024) {
        float v = mm[i];
        s += v; q += v * v;
    }
    ssum[tid] = s; ssq[tid] = q;
    __syncthreads();
    for (int st = 512; st > 0; st >>= 1) {
        if (tid < st) { ssum[tid] += ssum[tid + st]; ssq[tid] += ssq[tid + st]; }
        __syncthreads();
    }
    if (tid == 0) {
        stats[0] = ssum[0];
        stats[1] = ssq[0];
    }
}

// ---------- normalize + bilinear 49x49 -> 256x256 (stats are raw sums) ----------
__global__ __launch_bounds__(256) void bilinear_kernel(
    const float* __restrict__ mm, const float* __restrict__ stats,
    const float* __restrict__ gamma, const float* __restrict__ beta,
    float* __restrict__ out) {
    int idx = blockIdx.x * 256 + threadIdx.x;   // 16*256*256 = 1,048,576
    int b  = idx >> 16;
    int oy = (idx >> 8) & 255;
    int ox = idx & 255;
    const float scale = 49.0f / 256.0f;
    float cy = fminf(fmaxf((oy + 0.5f) * scale - 0.5f, 0.0f), 48.0f);
    int y0 = (int)cy; int y1 = min(y0 + 1, 48); float wy = cy - (float)y0;
    float cx = fminf(fmaxf((ox + 0.5f) * scale - 0.5f, 0.0f), 48.0f);
    int x0 = (int)cx; int x1 = min(x0 + 1, 48); float wx = cx - (float)x0;
    const float* mb = mm + (size_t)b * 2401;
    float v00 = mb[y0 * 49 + x0];
    float v01 = mb[y0 * 49 + x1];
    float v10 = mb[y1 * 49 + x0];
    float v11 = mb[y1 * 49 + x1];
    float r0 = v00 * (1.f - wy) + v10 * wy;
    float r1 = v01 * (1.f - wy) + v11 * wy;
    float v  = r0 * (1.f - wx) + r1 * wx;
    const float invN = 1.0f / 38416.0f;
    float mean = stats[0] * invN;
    float var  = stats[1] * invN - mean * mean;
    float rstd = rsqrtf(var + 1e-5f);
    v = (v - mean) * rstd * gamma[0] + beta[0];
    out[idx] = v;
}

extern "C" void kernel_launch(void* const* d_in, const int* in_sizes, int n_in,
                              void* d_out, int out_size, void* d_ws, size_t ws_size,
                              hipStream_t stream) {
    const float* S     = (const float*)d_in[0];   // (16,256,64,64)
    const float* D     = (const float*)d_in[1];   // (16,256,16,16)
    const float* gamma = (const float*)d_in[2];   // (1,)
    const float* beta  = (const float*)d_in[3];   // (1,)
    float* out = (float*)d_out;                   // (16,1,256,256)

    char* ws = (char*)d_ws;
    const size_t sizeDt = (size_t)16 * 256 * 256 * 2;        //  2,097,152
    const size_t sizeMm = (size_t)38416 * 4;                 //    153,664
    const size_t sizeP  = (size_t)16 * 64 * 16 * 52 * 4;     //  3,407,872
    const size_t sizeI  = (size_t)16 * 32 * SLAB_BYTES;      // 34,078,720
    const size_t offDt = 0;
    const size_t offMm = offDt + sizeDt;
    const size_t offStats = offMm + sizeMm;
    const size_t offP = (offStats + 2 * sizeof(float) + 255) & ~(size_t)255;
    const size_t offI = offP + sizeP;
    const size_t needFast = offI + sizeI;

    bool fast = (ws_size >= needFast);
    float* mm;
    float* stats;
    if (fast) {
        mm    = (float*)(ws + offMm);
        stats = (float*)(ws + offStats);
    } else {
        mm    = (float*)ws;
        stats = (float*)(ws + sizeMm);
    }

    if (fast) {
        unsigned short* Dt = (unsigned short*)(ws + offDt);
        float* P = (float*)(ws + offP);
        char* I = ws + offI;
        transposeD<<<dim3(8, 8, 16), dim3(32, 8), 0, stream>>>(D, Dt, stats);
        transposeS1<<<512, 256, 0, stream>>>(S, I);
        conv_fused<<<1024, 256, 0, stream>>>(I, Dt, P);
        reduce_kernel<<<151, 256, 0, stream>>>(P, mm, stats);
    } else {
        conv_naive<<<16 * 2401, 256, 0, stream>>>(S, D, mm);
        stats_kernel<<<1, 1024, 0, stream>>>(mm, stats);
    }
    bilinear_kernel<<<4096, 256, 0, stream>>>(mm, stats, gamma, beta, out);
}